// Round 17
// baseline (258.218 us; speedup 1.0000x reference)
//
#include <hip/hip_runtime.h>
#include <hip/hip_bf16.h>

// LocalPPM — R16 ABLATION ROUND (R11 base, best=32.5us).
// kf<1> = softmax phases only (x24), kf<2> = phase-2 full (x6),
// kf<3> = phase-2 loads-only (x6), kf<0> = real full kernel -> out.
// Each variant dispatch > 40us poison-fills -> per-phase counters surface.
// Keepalive via LDS reads + asm sinks (rule #17); sink buffer in ws.

#define PX 3136   // 56*56
#define CS 3136   // channel plane stride (H*W)

typedef float f4a __attribute__((ext_vector_type(4), aligned(4)));

// xcd = bid&7 owns batch b = xcd>>1, image-half = xcd&1 (49 strips of 32 px).
#define DECODE_SLAB()                                   \
    const int bid   = blockIdx.x;                       \
    const int xcd   = bid & 7;                          \
    const int b     = xcd >> 1;                         \
    const int pbase = (((xcd & 1) * 49) + (bid >> 3)) * 32;

// block 1024 = 32 px x 32 ch-chunks (8 ch each); grid 392.  (R11, proven)
__global__ __launch_bounds__(1024) void k_dot(const float* __restrict__ x,
                                              float* __restrict__ dot) {
    DECODE_SLAB();
    const int px = threadIdx.x & 31;
    const int ck = threadIdx.x >> 5;               // 0..31 channel chunk (8 ch)
    const int p  = pbase + px;
    const int h  = p / 56;
    const int w  = p - h * 56;

    const bool vm2 = (h >= 2), vm1 = (h >= 1);
    const bool cv0 = (w >= 2), cv1 = (w >= 1), cv3 = (w <= 54), cv4 = (w <= 53);

    const float* xb  = x + (size_t)b * 256 * CS + (size_t)ck * 8 * CS;
    const float* cp  = xb + p;        // center (row h, col w)
    const float* pr2 = cp - 112;      // row h-2
    const float* pr1 = cp - 56;       // row h-1

    float a[13];
    #pragma unroll
    for (int i = 0; i < 13; ++i) a[i] = 0.f;

    // c == 0: masked scalar path (low tensor corner safety)
    {
        const float ctr = cp[0];
        float n;
        n = (vm2 && cv0) ? pr2[-2] : 0.f; a[0]  = fmaf(ctr, n, a[0]);
        n = (vm2 && cv1) ? pr2[-1] : 0.f; a[1]  = fmaf(ctr, n, a[1]);
        n =  vm2         ? pr2[ 0] : 0.f; a[2]  = fmaf(ctr, n, a[2]);
        n = (vm2 && cv3) ? pr2[ 1] : 0.f; a[3]  = fmaf(ctr, n, a[3]);
        n = (vm2 && cv4) ? pr2[ 2] : 0.f; a[4]  = fmaf(ctr, n, a[4]);
        n = (vm1 && cv0) ? pr1[-2] : 0.f; a[5]  = fmaf(ctr, n, a[5]);
        n = (vm1 && cv1) ? pr1[-1] : 0.f; a[6]  = fmaf(ctr, n, a[6]);
        n =  vm1         ? pr1[ 0] : 0.f; a[7]  = fmaf(ctr, n, a[7]);
        n = (vm1 && cv3) ? pr1[ 1] : 0.f; a[8]  = fmaf(ctr, n, a[8]);
        n = (vm1 && cv4) ? pr1[ 2] : 0.f; a[9]  = fmaf(ctr, n, a[9]);
        n =  cv0         ? cp [-2] : 0.f; a[10] = fmaf(ctr, n, a[10]);
        n =  cv1         ? cp [-1] : 0.f; a[11] = fmaf(ctr, n, a[11]);
        a[12] = fmaf(ctr, ctr, a[12]);
    }

    const bool tail_unsafe = (b == 3) && (ck == 31);   // high tensor corner

    #pragma unroll
    for (int c = 1; c < 8; ++c) {
        const int o = c * CS;
        if (c == 7 && tail_unsafe) {
            const f4a   t2  = *(const f4a*)(pr2 + o - 2);
            const float t2e = pr2[o + 2];
            const f4a   t1  = *(const f4a*)(pr1 + o - 2);
            const float t1e = pr1[o + 2];
            const float c0  = cp[o - 2], c1 = cp[o - 1], ctr = cp[o];
            a[0]  = fmaf(ctr, t2.x, a[0]);
            a[1]  = fmaf(ctr, t2.y, a[1]);
            a[2]  = fmaf(ctr, t2.z, a[2]);
            a[3]  = fmaf(ctr, t2.w, a[3]);
            a[4]  = fmaf(ctr, t2e,  a[4]);
            a[5]  = fmaf(ctr, t1.x, a[5]);
            a[6]  = fmaf(ctr, t1.y, a[6]);
            a[7]  = fmaf(ctr, t1.z, a[7]);
            a[8]  = fmaf(ctr, t1.w, a[8]);
            a[9]  = fmaf(ctr, t1e,  a[9]);
            a[10] = fmaf(ctr, c0,   a[10]);
            a[11] = fmaf(ctr, c1,   a[11]);
            a[12] = fmaf(ctr, ctr,  a[12]);
        } else {
            const f4a   t2  = *(const f4a*)(pr2 + o - 2);
            const float t2e = pr2[o + 2];
            const f4a   t1  = *(const f4a*)(pr1 + o - 2);
            const float t1e = pr1[o + 2];
            const f4a   t0  = *(const f4a*)(cp  + o - 2);
            const float ctr = t0.z;
            a[0]  = fmaf(ctr, t2.x, a[0]);
            a[1]  = fmaf(ctr, t2.y, a[1]);
            a[2]  = fmaf(ctr, t2.z, a[2]);
            a[3]  = fmaf(ctr, t2.w, a[3]);
            a[4]  = fmaf(ctr, t2e,  a[4]);
            a[5]  = fmaf(ctr, t1.x, a[5]);
            a[6]  = fmaf(ctr, t1.y, a[6]);
            a[7]  = fmaf(ctr, t1.z, a[7]);
            a[8]  = fmaf(ctr, t1.w, a[8]);
            a[9]  = fmaf(ctr, t1e,  a[9]);
            a[10] = fmaf(ctr, t0.x, a[10]);
            a[11] = fmaf(ctr, t0.y, a[11]);
            a[12] = fmaf(ctr, ctr,  a[12]);
        }
    }

    __shared__ float part[32][13][32];             // 53.2 KB
    #pragma unroll
    for (int i = 0; i < 13; ++i) part[ck][i][px] = a[i];
    __syncthreads();

    if (threadIdx.x < 13 * 32) {
        const int acc = threadIdx.x >> 5, pp = threadIdx.x & 31;
        float s = 0.f;
        #pragma unroll
        for (int j = 0; j < 32; ++j) s += part[j][acc][pp];
        dot[((size_t)(b * 13 + acc)) * PX + pbase + pp] = s;
    }
}

// V=0: full (writes out). V=1: phases 1a-1c only. V=2: phase 2 only (dummy
// weights). V=3: phase 2 loads only (asm keepalive, no FMA/stores).
template <int V>
__global__ __launch_bounds__(1024) void kf(const float* __restrict__ x,
                                           const float* __restrict__ dot,
                                           const float* __restrict__ gptr,
                                           float* __restrict__ out,
                                           float* __restrict__ sink,
                                           int reps) {
    DECODE_SLAB();
    const int tid = threadIdx.x;
    const float* db = dot + (size_t)b * 13 * PX;

    __shared__ float s_lds[32][25];
    __shared__ float e_lds[32][25];
    __shared__ float inv_lds[32];

    if constexpr (V == 2) {        // deterministic dummy weights, same codegen
        if (tid < 800) {
            const int px = tid / 25, k = tid - (tid / 25) * 25;
            e_lds[px][k] = 0.04f;
        }
        if (tid < 32) inv_lds[tid] = 1.0f;
        __syncthreads();
    }

    float keep = 0.f;

    for (int rep = 0; rep < reps; ++rep) {
        asm volatile("" ::: "memory");

        if constexpr (V == 0 || V == 1) {
            // ---- phase 1a: sims into LDS ----
            if (tid < 800) {
                const int px = tid / 25, k = tid - (tid / 25) * 25;
                const int p = pbase + px;
                const int h = p / 56, w = p - (p / 56) * 56;
                const int dy = k / 5 - 2, dx = k % 5 - 2;
                const int rr = h + dy, cc = w + dx;
                const bool v = (rr >= 0) && (rr < 56) && (cc >= 0) && (cc < 56);
                float d = 0.f, n2 = 0.f;
                if (v) {
                    const int q = rr * 56 + cc;
                    n2 = db[12 * PX + q];
                    d  = (k <= 12) ? db[k * PX + p] : db[(24 - k) * PX + q];
                }
                const float cn = sqrtf(db[12 * PX + p]);
                s_lds[px][k] = d / fmaxf(sqrtf(n2) * cn, 1e-8f) * 10.f;
            }
            __syncthreads();

            // ---- phase 1b: rank + max + exp ----
            if (tid < 800) {
                const int px = tid / 25, k = tid - (tid / 25) * 25;
                const float sk = s_lds[px][k];
                int rank = 0;
                float m = sk;
                #pragma unroll
                for (int j = 0; j < 25; ++j) {
                    const float sj = s_lds[px][j];
                    rank += (int)((sj > sk) || ((sj == sk) && (j < k)));
                    m = fmaxf(m, sj);
                }
                e_lds[px][k] = (rank < 10) ? __expf(sk - m) : 0.f;
            }
            __syncthreads();

            // ---- phase 1c: per-pixel denom ----
            if (tid < 32) {
                float denom = 0.f;
                #pragma unroll
                for (int k = 0; k < 25; ++k) denom += e_lds[tid][k];
                inv_lds[tid] = 1.f / denom;
            }
            __syncthreads();
        }

        if constexpr (V == 0 || V == 2 || V == 3) {
            const int px  = tid & 31;
            const int sub = tid >> 5;              // 0..31, 8 channels each
            const int p   = pbase + px;
            const int h   = p / 56;
            const int w   = p - h * 56;

            const bool vm2 = (h >= 2), vm1 = (h >= 1);
            const bool vp1 = (h <= 54), vp2 = (h <= 53);
            const bool cv0 = (w >= 2), cv1 = (w >= 1);
            const bool cv3 = (w <= 54), cv4 = (w <= 53);

            const float* xb = x + ((size_t)b * 256 + sub * 8) * CS;

            if constexpr (V == 3) {
                // loads only, asm keepalive, minimal VALU
                #pragma unroll 2
                for (int ci = 0; ci < 8; ++ci) {
                    const float* xp = xb + ci * CS + p;
                    const bool unsafe = (b == 0 && sub == 0 && ci == 0) ||
                                        (b == 3 && sub == 31 && ci == 7);
                    if (!unsafe) {
                        #pragma unroll
                        for (int r = 0; r < 5; ++r) {
                            const float* rp = xp + (r - 2) * 56;
                            const f4a   v4 = *(const f4a*)(rp - 2);
                            const float s4 = rp[2];
                            asm volatile("" :: "v"(v4.x), "v"(v4.w), "v"(s4));
                            if (r == 2) keep = v4.z;
                        }
                    } else {
                        const float c0 = xp[0];
                        asm volatile("" :: "v"(c0));
                        keep = c0;
                    }
                }
            } else {
                const float g   = *gptr;
                const float inv = inv_lds[px];
                float wq[25];
                #pragma unroll
                for (int k = 0; k < 25; ++k) {
                    const int dy = k / 5 - 2, dx = k % 5 - 2;
                    const bool vr = (dy == -2) ? vm2 : (dy == -1) ? vm1
                                  : (dy == 0) ? true : (dy == 1) ? vp1 : vp2;
                    const bool vc = (dx == -2) ? cv0 : (dx == -1) ? cv1
                                  : (dx == 0) ? true : (dx == 1) ? cv3 : cv4;
                    wq[k] = (vr && vc) ? e_lds[px][k] * inv : 0.f;
                }

                float* ob = out + ((size_t)b * 256 + sub * 8) * CS;

                #pragma unroll 2
                for (int ci = 0; ci < 8; ++ci) {
                    const float* xp = xb + ci * CS + p;
                    const bool unsafe = (b == 0 && sub == 0 && ci == 0) ||
                                        (b == 3 && sub == 31 && ci == 7);
                    float y = 0.f, ctr;
                    if (!unsafe) {
                        #pragma unroll
                        for (int r = 0; r < 5; ++r) {
                            const float* rp = xp + (r - 2) * 56;
                            const f4a   v4 = *(const f4a*)(rp - 2);
                            const float s4 = rp[2];
                            if (r == 2) ctr = v4.z;
                            y = fmaf(wq[r*5+0], v4.x, y);
                            y = fmaf(wq[r*5+1], v4.y, y);
                            y = fmaf(wq[r*5+2], v4.z, y);
                            y = fmaf(wq[r*5+3], v4.w, y);
                            y = fmaf(wq[r*5+4], s4,   y);
                        }
                    } else {
                        ctr = xp[0];
                        #pragma unroll
                        for (int k = 0; k < 25; ++k) {
                            const int dy = k / 5 - 2, dx = k % 5 - 2;
                            const bool vr = (dy == -2) ? vm2 : (dy == -1) ? vm1
                                          : (dy == 0) ? true : (dy == 1) ? vp1 : vp2;
                            const bool vc = (dx == -2) ? cv0 : (dx == -1) ? cv1
                                          : (dx == 0) ? true : (dx == 1) ? cv3 : cv4;
                            const float xv = (vr && vc) ? xp[dy * 56 + dx] : 0.f;
                            y = fmaf(wq[k], xv, y);
                        }
                    }
                    if constexpr (V == 0) {
                        ob[ci * CS + p] = ctr + g * y;
                    } else {
                        keep += ctr + g * y;
                    }
                }
            }
        }

        if constexpr (V == 1) {
            keep += inv_lds[tid & 31] + e_lds[tid & 31][tid % 25];
        }
        __syncthreads();                           // LDS reuse across reps
    }

    if constexpr (V != 0) {
        sink[(size_t)blockIdx.x * 1024 + tid] = keep;
    }
}

extern "C" void kernel_launch(void* const* d_in, const int* in_sizes, int n_in,
                              void* d_out, int out_size, void* d_ws, size_t ws_size,
                              hipStream_t stream) {
    const float* x     = (const float*)d_in[0];
    const float* gamma = (const float*)d_in[1];
    float* out  = (float*)d_out;
    float* dot  = (float*)d_ws;                    // [4][13][3136] = 652 KB
    float* sink = dot + 4 * 13 * PX;               // 392*1024 floats = 1.6 MB

    k_dot<<<392, 1024, 0, stream>>>(x, dot);
    kf<1><<<392, 1024, 0, stream>>>(x, dot, gamma, out, sink, 24);
    kf<2><<<392, 1024, 0, stream>>>(x, dot, gamma, out, sink, 6);
    kf<3><<<392, 1024, 0, stream>>>(x, dot, gamma, out, sink, 6);
    kf<0><<<392, 1024, 0, stream>>>(x, dot, gamma, out, sink, 1);
}

// Round 18
// 38.456 us; speedup vs baseline: 6.7146x; 6.7146x over previous
//
#include <hip/hip_runtime.h>
#include <hip/hip_bf16.h>

// LocalPPM: B=4, C=256, H=W=56, R=2 (5x5 -> K2=25), TOPK=10, TAU=0.1, EPS=1e-8
// out = x + gamma * sum_k softmax_top10(cos_sim(center,nbr)/TAU) * nbr
//
// R17: R16 ablation showed phase-2 loads-only == phase-2 full (16.3us/rep):
// k_fused is bound by bytes pulled through the L1/L2 load path (800B/thread),
// not FMA/occupancy/VGPR. Fix: LDS-stage x (group of 32 channels x 6 clamped
// rows x 56 cols = 43KB), taps read from LDS (69TB/s pipe, <=2-way banks).
// L2 bytes/thread 800 -> 336. Corner peel eliminated (stages are in-plane).

#define PX 3136   // 56*56
#define CS 3136   // channel plane stride (H*W)

typedef float f4a __attribute__((ext_vector_type(4), aligned(4)));

// xcd = bid&7 owns batch b = xcd>>1, image-half = xcd&1 (49 strips of 32 px).
#define DECODE_SLAB()                                   \
    const int bid   = blockIdx.x;                       \
    const int xcd   = bid & 7;                          \
    const int b     = xcd >> 1;                         \
    const int pbase = (((xcd & 1) * 49) + (bid >> 3)) * 32;

// block 1024 = 32 px x 32 ch-chunks (8 ch each); grid 392.  (R11, proven)
__global__ __launch_bounds__(1024) void k_dot(const float* __restrict__ x,
                                              float* __restrict__ dot) {
    DECODE_SLAB();
    const int px = threadIdx.x & 31;
    const int ck = threadIdx.x >> 5;               // 0..31 channel chunk (8 ch)
    const int p  = pbase + px;
    const int h  = p / 56;
    const int w  = p - h * 56;

    const bool vm2 = (h >= 2), vm1 = (h >= 1);
    const bool cv0 = (w >= 2), cv1 = (w >= 1), cv3 = (w <= 54), cv4 = (w <= 53);

    const float* xb  = x + (size_t)b * 256 * CS + (size_t)ck * 8 * CS;
    const float* cp  = xb + p;        // center (row h, col w)
    const float* pr2 = cp - 112;      // row h-2
    const float* pr1 = cp - 56;       // row h-1

    float a[13];
    #pragma unroll
    for (int i = 0; i < 13; ++i) a[i] = 0.f;

    // c == 0: masked scalar path (low tensor corner safety)
    {
        const float ctr = cp[0];
        float n;
        n = (vm2 && cv0) ? pr2[-2] : 0.f; a[0]  = fmaf(ctr, n, a[0]);
        n = (vm2 && cv1) ? pr2[-1] : 0.f; a[1]  = fmaf(ctr, n, a[1]);
        n =  vm2         ? pr2[ 0] : 0.f; a[2]  = fmaf(ctr, n, a[2]);
        n = (vm2 && cv3) ? pr2[ 1] : 0.f; a[3]  = fmaf(ctr, n, a[3]);
        n = (vm2 && cv4) ? pr2[ 2] : 0.f; a[4]  = fmaf(ctr, n, a[4]);
        n = (vm1 && cv0) ? pr1[-2] : 0.f; a[5]  = fmaf(ctr, n, a[5]);
        n = (vm1 && cv1) ? pr1[-1] : 0.f; a[6]  = fmaf(ctr, n, a[6]);
        n =  vm1         ? pr1[ 0] : 0.f; a[7]  = fmaf(ctr, n, a[7]);
        n = (vm1 && cv3) ? pr1[ 1] : 0.f; a[8]  = fmaf(ctr, n, a[8]);
        n = (vm1 && cv4) ? pr1[ 2] : 0.f; a[9]  = fmaf(ctr, n, a[9]);
        n =  cv0         ? cp [-2] : 0.f; a[10] = fmaf(ctr, n, a[10]);
        n =  cv1         ? cp [-1] : 0.f; a[11] = fmaf(ctr, n, a[11]);
        a[12] = fmaf(ctr, ctr, a[12]);
    }

    const bool tail_unsafe = (b == 3) && (ck == 31);   // high tensor corner

    #pragma unroll
    for (int c = 1; c < 8; ++c) {
        const int o = c * CS;
        if (c == 7 && tail_unsafe) {
            const f4a   t2  = *(const f4a*)(pr2 + o - 2);
            const float t2e = pr2[o + 2];
            const f4a   t1  = *(const f4a*)(pr1 + o - 2);
            const float t1e = pr1[o + 2];
            const float c0  = cp[o - 2], c1 = cp[o - 1], ctr = cp[o];
            a[0]  = fmaf(ctr, t2.x, a[0]);
            a[1]  = fmaf(ctr, t2.y, a[1]);
            a[2]  = fmaf(ctr, t2.z, a[2]);
            a[3]  = fmaf(ctr, t2.w, a[3]);
            a[4]  = fmaf(ctr, t2e,  a[4]);
            a[5]  = fmaf(ctr, t1.x, a[5]);
            a[6]  = fmaf(ctr, t1.y, a[6]);
            a[7]  = fmaf(ctr, t1.z, a[7]);
            a[8]  = fmaf(ctr, t1.w, a[8]);
            a[9]  = fmaf(ctr, t1e,  a[9]);
            a[10] = fmaf(ctr, c0,   a[10]);
            a[11] = fmaf(ctr, c1,   a[11]);
            a[12] = fmaf(ctr, ctr,  a[12]);
        } else {
            const f4a   t2  = *(const f4a*)(pr2 + o - 2);
            const float t2e = pr2[o + 2];
            const f4a   t1  = *(const f4a*)(pr1 + o - 2);
            const float t1e = pr1[o + 2];
            const f4a   t0  = *(const f4a*)(cp  + o - 2);
            const float ctr = t0.z;
            a[0]  = fmaf(ctr, t2.x, a[0]);
            a[1]  = fmaf(ctr, t2.y, a[1]);
            a[2]  = fmaf(ctr, t2.z, a[2]);
            a[3]  = fmaf(ctr, t2.w, a[3]);
            a[4]  = fmaf(ctr, t2e,  a[4]);
            a[5]  = fmaf(ctr, t1.x, a[5]);
            a[6]  = fmaf(ctr, t1.y, a[6]);
            a[7]  = fmaf(ctr, t1.z, a[7]);
            a[8]  = fmaf(ctr, t1.w, a[8]);
            a[9]  = fmaf(ctr, t1e,  a[9]);
            a[10] = fmaf(ctr, t0.x, a[10]);
            a[11] = fmaf(ctr, t0.y, a[11]);
            a[12] = fmaf(ctr, ctr,  a[12]);
        }
    }

    __shared__ float part[32][13][32];             // 53.2 KB
    #pragma unroll
    for (int i = 0; i < 13; ++i) part[ck][i][px] = a[i];
    __syncthreads();

    if (threadIdx.x < 13 * 32) {
        const int acc = threadIdx.x >> 5, pp = threadIdx.x & 31;
        float s = 0.f;
        #pragma unroll
        for (int j = 0; j < 32; ++j) s += part[j][acc][pp];
        dot[((size_t)(b * 13 + acc)) * PX + pbase + pp] = s;
    }
}

// Fused weights + output with LDS-staged x. block 1024 = 32 px x 32 subs.
// 8 channel-groups of 32: stage 32 ch x 6 rows x 56 cols, compute from LDS.
__global__ __launch_bounds__(1024) void k_fused(const float* __restrict__ x,
                                                const float* __restrict__ dot,
                                                const float* __restrict__ gptr,
                                                float* __restrict__ out) {
    DECODE_SLAB();
    const int tid = threadIdx.x;
    const float* db = dot + (size_t)b * 13 * PX;

    __shared__ float dlds[32 * 336 + 8];           // 43 KB (+pad, +4 front)
    __shared__ float s_lds[32][25];
    __shared__ float e_lds[32][25];
    __shared__ float inv_lds[32];

    // ---- phase 1a: sims into LDS ----
    if (tid < 800) {
        const int px = tid / 25, k = tid - (tid / 25) * 25;
        const int p = pbase + px;
        const int h = p / 56, w = p - (p / 56) * 56;
        const int dy = k / 5 - 2, dx = k % 5 - 2;
        const int rr = h + dy, cc = w + dx;
        const bool v = (rr >= 0) && (rr < 56) && (cc >= 0) && (cc < 56);
        float d = 0.f, n2 = 0.f;
        if (v) {
            const int q = rr * 56 + cc;
            n2 = db[12 * PX + q];
            d  = (k <= 12) ? db[k * PX + p] : db[(24 - k) * PX + q];
        }
        const float cn = sqrtf(db[12 * PX + p]);
        s_lds[px][k] = d / fmaxf(sqrtf(n2) * cn, 1e-8f) * 10.f;
    }
    __syncthreads();

    // ---- phase 1b: rank (exact top-10, JAX tie-break) + max + exp ----
    if (tid < 800) {
        const int px = tid / 25, k = tid - (tid / 25) * 25;
        const float sk = s_lds[px][k];
        int rank = 0;
        float m = sk;
        #pragma unroll
        for (int j = 0; j < 25; ++j) {
            const float sj = s_lds[px][j];
            rank += (int)((sj > sk) || ((sj == sk) && (j < k)));
            m = fmaxf(m, sj);
        }
        e_lds[px][k] = (rank < 10) ? __expf(sk - m) : 0.f;
    }
    __syncthreads();

    // ---- phase 1c: per-pixel denom ----
    if (tid < 32) {
        float denom = 0.f;
        #pragma unroll
        for (int k = 0; k < 25; ++k) denom += e_lds[tid][k];
        inv_lds[tid] = 1.f / denom;
    }
    __syncthreads();

    // ---- per-thread geometry ----
    const int px  = tid & 31;
    const int sub = tid >> 5;                      // 0..31: channel within group
    const int p   = pbase + px;
    const int h   = p / 56;
    const int w   = p - h * 56;
    const float g = *gptr;

    const int r0    = pbase / 56;                  // first row of strip
    const int rbase = r0 - 2;                      // staged row 0 (may be <0)
    const int lrow  = h - rbase;                   // center's staged row (2 or 3)

    const bool vm2 = (h >= 2), vm1 = (h >= 1), vp1 = (h <= 54), vp2 = (h <= 53);
    const bool cv0 = (w >= 2), cv1 = (w >= 1), cv3 = (w <= 54), cv4 = (w <= 53);

    // pre-masked weights: invalid tap => weight 0 (staged clamp-garbage x0)
    const float inv = inv_lds[px];
    float wq[25];
    #pragma unroll
    for (int k = 0; k < 25; ++k) {
        const int dy = k / 5 - 2, dx = k % 5 - 2;
        const bool vr = (dy == -2) ? vm2 : (dy == -1) ? vm1 : (dy == 0) ? true
                      : (dy == 1) ? vp1 : vp2;
        const bool vc = (dx == -2) ? cv0 : (dx == -1) ? cv1 : (dx == 0) ? true
                      : (dx == 1) ? cv3 : cv4;
        wq[k] = (vr && vc) ? e_lds[px][k] * inv : 0.f;
    }

    // clamped source rows for the 6 staged rows
    int srow[6];
    #pragma unroll
    for (int j = 0; j < 6; ++j) {
        int r = rbase + j;
        srow[j] = (r < 0) ? 0 : ((r > 55) ? 55 : r);
    }

    const float* xb = x   + (size_t)b * 256 * CS;
    float*       ob = out + (size_t)b * 256 * CS;
    const int cbl = 4 + sub * 336 + lrow * 56 + w; // this thread's LDS center

    // ---- 8 groups of 32 channels: stage -> compute ----
    for (int grp = 0; grp < 8; ++grp) {
        __syncthreads();                           // protect dlds reuse
        // stage: 32 ch x 6 rows x 14 dwordx4 = 2688 units, 16B-aligned
        for (int j = tid; j < 2688; j += 1024) {
            const int ch  = j / 84;
            const int rem = j - ch * 84;
            const int rj  = rem / 14;
            const int q4  = rem - rj * 14;
            const float* src = xb + ((size_t)(grp * 32 + ch)) * CS
                             + srow[rj] * 56 + q4 * 4;
            *(f4a*)(dlds + 4 + ch * 336 + rj * 56 + q4 * 4) = *(const f4a*)src;
        }
        __syncthreads();

        // compute: this thread's channel = grp*32 + sub, 25 taps from LDS
        float y = 0.f;
        #pragma unroll
        for (int r = 0; r < 5; ++r) {
            const int base = cbl + (r - 2) * 56;
            y = fmaf(wq[r*5+0], dlds[base - 2], y);
            y = fmaf(wq[r*5+1], dlds[base - 1], y);
            y = fmaf(wq[r*5+2], dlds[base    ], y);
            y = fmaf(wq[r*5+3], dlds[base + 1], y);
            y = fmaf(wq[r*5+4], dlds[base + 2], y);
        }
        const float ctr = dlds[cbl];
        ob[((size_t)(grp * 32 + sub)) * CS + p] = ctr + g * y;
    }
}

extern "C" void kernel_launch(void* const* d_in, const int* in_sizes, int n_in,
                              void* d_out, int out_size, void* d_ws, size_t ws_size,
                              hipStream_t stream) {
    const float* x     = (const float*)d_in[0];
    const float* gamma = (const float*)d_in[1];
    float* out = (float*)d_out;
    float* dot = (float*)d_ws;                 // [4][13][3136]

    k_dot<<<392, 1024, 0, stream>>>(x, dot);
    k_fused<<<392, 1024, 0, stream>>>(x, dot, gamma, out);
}

// Round 19
// 32.904 us; speedup vs baseline: 7.8475x; 1.1687x over previous
//
#include <hip/hip_runtime.h>
#include <hip/hip_bf16.h>

// LocalPPM: B=4, C=256, H=W=56, R=2 (5x5 -> K2=25), TOPK=10, TAU=0.1, EPS=1e-8
// out = x + gamma * sum_k softmax_top10(cos_sim(center,nbr)/TAU) * nbr
//
// R18: k_dot unchanged (R11, ~7us). k_fused = pixel-PAIR formulation:
// thread owns (p0,p0+1) x 8 channels. Per row, 1 b128 + 1 b64 load serves
// both pixels' 5 dx-taps (10 taps / 2 insts) -> 5 VMEM insts per output,
// half of R11's 10. Mechanism (R16 ablation + k_dot cross-check): k_fused
// time scales with VMEM wave-inst count (loads-only == full, 16.3us @ 80
// insts; k_dot 7us @ 40), so halving insts should halve phase-2 time.
// 512-thr block (16 pairs x 32 subs) gives VGPR room for wqA/wqB[25].

#define PX 3136   // 56*56
#define CS 3136   // channel plane stride (H*W)

typedef float f4a __attribute__((ext_vector_type(4), aligned(4)));
typedef float f2a __attribute__((ext_vector_type(2), aligned(4)));

// xcd = bid&7 owns batch b = xcd>>1, image-half = xcd&1 (49 strips of 32 px).
#define DECODE_SLAB()                                   \
    const int bid   = blockIdx.x;                       \
    const int xcd   = bid & 7;                          \
    const int b     = xcd >> 1;                         \
    const int pbase = (((xcd & 1) * 49) + (bid >> 3)) * 32;

// block 1024 = 32 px x 32 ch-chunks (8 ch each); grid 392.  (R11, proven)
__global__ __launch_bounds__(1024) void k_dot(const float* __restrict__ x,
                                              float* __restrict__ dot) {
    DECODE_SLAB();
    const int px = threadIdx.x & 31;
    const int ck = threadIdx.x >> 5;               // 0..31 channel chunk (8 ch)
    const int p  = pbase + px;
    const int h  = p / 56;
    const int w  = p - h * 56;

    const bool vm2 = (h >= 2), vm1 = (h >= 1);
    const bool cv0 = (w >= 2), cv1 = (w >= 1), cv3 = (w <= 54), cv4 = (w <= 53);

    const float* xb  = x + (size_t)b * 256 * CS + (size_t)ck * 8 * CS;
    const float* cp  = xb + p;        // center (row h, col w)
    const float* pr2 = cp - 112;      // row h-2
    const float* pr1 = cp - 56;       // row h-1

    float a[13];
    #pragma unroll
    for (int i = 0; i < 13; ++i) a[i] = 0.f;

    // c == 0: masked scalar path (low tensor corner safety)
    {
        const float ctr = cp[0];
        float n;
        n = (vm2 && cv0) ? pr2[-2] : 0.f; a[0]  = fmaf(ctr, n, a[0]);
        n = (vm2 && cv1) ? pr2[-1] : 0.f; a[1]  = fmaf(ctr, n, a[1]);
        n =  vm2         ? pr2[ 0] : 0.f; a[2]  = fmaf(ctr, n, a[2]);
        n = (vm2 && cv3) ? pr2[ 1] : 0.f; a[3]  = fmaf(ctr, n, a[3]);
        n = (vm2 && cv4) ? pr2[ 2] : 0.f; a[4]  = fmaf(ctr, n, a[4]);
        n = (vm1 && cv0) ? pr1[-2] : 0.f; a[5]  = fmaf(ctr, n, a[5]);
        n = (vm1 && cv1) ? pr1[-1] : 0.f; a[6]  = fmaf(ctr, n, a[6]);
        n =  vm1         ? pr1[ 0] : 0.f; a[7]  = fmaf(ctr, n, a[7]);
        n = (vm1 && cv3) ? pr1[ 1] : 0.f; a[8]  = fmaf(ctr, n, a[8]);
        n = (vm1 && cv4) ? pr1[ 2] : 0.f; a[9]  = fmaf(ctr, n, a[9]);
        n =  cv0         ? cp [-2] : 0.f; a[10] = fmaf(ctr, n, a[10]);
        n =  cv1         ? cp [-1] : 0.f; a[11] = fmaf(ctr, n, a[11]);
        a[12] = fmaf(ctr, ctr, a[12]);
    }

    const bool tail_unsafe = (b == 3) && (ck == 31);   // high tensor corner

    #pragma unroll
    for (int c = 1; c < 8; ++c) {
        const int o = c * CS;
        if (c == 7 && tail_unsafe) {
            const f4a   t2  = *(const f4a*)(pr2 + o - 2);
            const float t2e = pr2[o + 2];
            const f4a   t1  = *(const f4a*)(pr1 + o - 2);
            const float t1e = pr1[o + 2];
            const float c0  = cp[o - 2], c1 = cp[o - 1], ctr = cp[o];
            a[0]  = fmaf(ctr, t2.x, a[0]);
            a[1]  = fmaf(ctr, t2.y, a[1]);
            a[2]  = fmaf(ctr, t2.z, a[2]);
            a[3]  = fmaf(ctr, t2.w, a[3]);
            a[4]  = fmaf(ctr, t2e,  a[4]);
            a[5]  = fmaf(ctr, t1.x, a[5]);
            a[6]  = fmaf(ctr, t1.y, a[6]);
            a[7]  = fmaf(ctr, t1.z, a[7]);
            a[8]  = fmaf(ctr, t1.w, a[8]);
            a[9]  = fmaf(ctr, t1e,  a[9]);
            a[10] = fmaf(ctr, c0,   a[10]);
            a[11] = fmaf(ctr, c1,   a[11]);
            a[12] = fmaf(ctr, ctr,  a[12]);
        } else {
            const f4a   t2  = *(const f4a*)(pr2 + o - 2);
            const float t2e = pr2[o + 2];
            const f4a   t1  = *(const f4a*)(pr1 + o - 2);
            const float t1e = pr1[o + 2];
            const f4a   t0  = *(const f4a*)(cp  + o - 2);
            const float ctr = t0.z;
            a[0]  = fmaf(ctr, t2.x, a[0]);
            a[1]  = fmaf(ctr, t2.y, a[1]);
            a[2]  = fmaf(ctr, t2.z, a[2]);
            a[3]  = fmaf(ctr, t2.w, a[3]);
            a[4]  = fmaf(ctr, t2e,  a[4]);
            a[5]  = fmaf(ctr, t1.x, a[5]);
            a[6]  = fmaf(ctr, t1.y, a[6]);
            a[7]  = fmaf(ctr, t1.z, a[7]);
            a[8]  = fmaf(ctr, t1.w, a[8]);
            a[9]  = fmaf(ctr, t1e,  a[9]);
            a[10] = fmaf(ctr, t0.x, a[10]);
            a[11] = fmaf(ctr, t0.y, a[11]);
            a[12] = fmaf(ctr, ctr,  a[12]);
        }
    }

    __shared__ float part[32][13][32];             // 53.2 KB
    #pragma unroll
    for (int i = 0; i < 13; ++i) part[ck][i][px] = a[i];
    __syncthreads();

    if (threadIdx.x < 13 * 32) {
        const int acc = threadIdx.x >> 5, pp = threadIdx.x & 31;
        float s = 0.f;
        #pragma unroll
        for (int j = 0; j < 32; ++j) s += part[j][acc][pp];
        dot[((size_t)(b * 13 + acc)) * PX + pbase + pp] = s;
    }
}

// Fused weights + output, pixel-pair form. block 512 = 16 pairs x 32 subs
// (8 ch each); grid 392, same slab decode.
__global__ __launch_bounds__(512) void k_fused(const float* __restrict__ x,
                                               const float* __restrict__ dot,
                                               const float* __restrict__ gptr,
                                               float* __restrict__ out) {
    DECODE_SLAB();
    const int tid = threadIdx.x;
    const float* db = dot + (size_t)b * 13 * PX;

    __shared__ float s_lds[32][25];
    __shared__ float e_lds[32][25];
    __shared__ float inv_lds[32];

    // ---- phase 1a: sims into LDS (800 items over 512 threads) ----
    #pragma unroll
    for (int i = tid; i < 800; i += 512) {
        const int px = i / 25, k = i - px * 25;
        const int p = pbase + px;
        const int h = p / 56, w = p - (p / 56) * 56;
        const int dy = k / 5 - 2, dx = k % 5 - 2;
        const int rr = h + dy, cc = w + dx;
        const bool v = (rr >= 0) && (rr < 56) && (cc >= 0) && (cc < 56);
        float d = 0.f, n2 = 0.f;
        if (v) {
            const int q = rr * 56 + cc;
            n2 = db[12 * PX + q];
            d  = (k <= 12) ? db[k * PX + p] : db[(24 - k) * PX + q];
        }
        const float cn = sqrtf(db[12 * PX + p]);
        s_lds[px][k] = d / fmaxf(sqrtf(n2) * cn, 1e-8f) * 10.f;
    }
    __syncthreads();

    // ---- phase 1b: rank (exact top-10, JAX tie-break) + max + exp ----
    #pragma unroll
    for (int i = tid; i < 800; i += 512) {
        const int px = i / 25, k = i - px * 25;
        const float sk = s_lds[px][k];
        int rank = 0;
        float m = sk;
        #pragma unroll
        for (int j = 0; j < 25; ++j) {
            const float sj = s_lds[px][j];
            rank += (int)((sj > sk) || ((sj == sk) && (j < k)));
            m = fmaxf(m, sj);
        }
        e_lds[px][k] = (rank < 10) ? __expf(sk - m) : 0.f;
    }
    __syncthreads();

    // ---- phase 1c: per-pixel denom ----
    if (tid < 32) {
        float denom = 0.f;
        #pragma unroll
        for (int k = 0; k < 25; ++k) denom += e_lds[tid][k];
        inv_lds[tid] = 1.f / denom;
    }
    __syncthreads();

    // ---- phase 2: pixel pair (p0, p0+1) x 8 channels ----
    const int pair = tid & 15;
    const int sub  = tid >> 4;                     // 0..31, 8 channels each
    const int i0   = pair * 2;                     // LDS pixel index 0..30
    const int p0   = pbase + i0;                   // even; pair shares a row
    const int h    = p0 / 56;
    const int w0   = p0 - h * 56;                  // even, <= 54
    const float g  = *gptr;

    // premasked weights for both pixels (invalid tap -> 0)
    const float invA = inv_lds[i0];
    const float invB = inv_lds[i0 + 1];
    float wqA[25], wqB[25];
    #pragma unroll
    for (int k = 0; k < 25; ++k) {
        const int dy = k / 5 - 2, dx = k % 5 - 2;
        const int rr = h + dy;
        const bool vr = (rr >= 0) && (rr < 56);
        const int ca = w0 + dx, cb = ca + 1;
        wqA[k] = (vr && ca >= 0 && ca < 56) ? e_lds[i0][k] * invA : 0.f;
        wqB[k] = (vr && cb >= 0 && cb < 56) ? e_lds[i0 + 1][k] * invB : 0.f;
    }

    const float* xb = x   + ((size_t)b * 256 + sub * 8) * CS;
    float*       ob = out + ((size_t)b * 256 + sub * 8) * CS;

    #pragma unroll 2
    for (int ci = 0; ci < 8; ++ci) {
        const float* xp = xb + ci * CS + p0;
        const bool unsafe = (b == 0 && sub == 0 && ci == 0) ||
                            (b == 3 && sub == 31 && ci == 7);
        float y0 = 0.f, y1 = 0.f, c0, c1;
        if (!unsafe) {
            #pragma unroll
            for (int r = 0; r < 5; ++r) {
                const float* rp = xp + (r - 2) * 56;
                const f4a lo = *(const f4a*)(rp - 2);   // cols w0-2..w0+1
                const f2a hi = *(const f2a*)(rp + 2);   // cols w0+2..w0+3
                if (r == 2) { c0 = lo.z; c1 = lo.w; }
                y0 = fmaf(wqA[r*5+0], lo.x, y0);
                y0 = fmaf(wqA[r*5+1], lo.y, y0);
                y0 = fmaf(wqA[r*5+2], lo.z, y0);
                y0 = fmaf(wqA[r*5+3], lo.w, y0);
                y0 = fmaf(wqA[r*5+4], hi.x, y0);
                y1 = fmaf(wqB[r*5+0], lo.y, y1);
                y1 = fmaf(wqB[r*5+1], lo.z, y1);
                y1 = fmaf(wqB[r*5+2], lo.w, y1);
                y1 = fmaf(wqB[r*5+3], hi.x, y1);
                y1 = fmaf(wqB[r*5+4], hi.y, y1);
            }
        } else {
            c0 = xp[0];
            c1 = xp[1];
            #pragma unroll
            for (int k = 0; k < 25; ++k) {
                const int dy = k / 5 - 2, dx = k % 5 - 2;
                const int rr = h + dy;
                const bool vr = (rr >= 0) && (rr < 56);
                const int ca = w0 + dx, cb = ca + 1;
                const float xa = (vr && ca >= 0 && ca < 56)
                               ? xp[dy * 56 + dx] : 0.f;
                const float xbv = (vr && cb >= 0 && cb < 56)
                               ? xp[dy * 56 + dx + 1] : 0.f;
                y0 = fmaf(wqA[k], xa,  y0);
                y1 = fmaf(wqB[k], xbv, y1);
            }
        }
        f2a o2;
        o2.x = c0 + g * y0;
        o2.y = c1 + g * y1;
        *(f2a*)(ob + ci * CS + p0) = o2;           // 8B-aligned (p0 even)
    }
}

extern "C" void kernel_launch(void* const* d_in, const int* in_sizes, int n_in,
                              void* d_out, int out_size, void* d_ws, size_t ws_size,
                              hipStream_t stream) {
    const float* x     = (const float*)d_in[0];
    const float* gamma = (const float*)d_in[1];
    float* out = (float*)d_out;
    float* dot = (float*)d_ws;                 // [4][13][3136]

    k_dot<<<392, 1024, 0, stream>>>(x, dot);
    k_fused<<<392, 512, 0, stream>>>(x, dot, gamma, out);
}